// Round 7
// baseline (275.835 us; speedup 1.0000x reference)
//
#include <hip/hip_runtime.h>

#define B 8
#define C 256
#define HW 16384
#define HALF 8192
#define NSEG 256
#define NCH 32            // hist chunks per batch
#define CHUNK 512         // pixels per chunk
#define NROW (B * C)      // 2048 (b,c) rows
#define NMAIN (NROW * 2)  // 4096 main blocks (one per row-half)

// ws layout:
//   [0, 262144)         : int   hist[B][NCH][NSEG]        256 KiB
//   [262144, 393216)    : u8    ids8[B][HW]               128 KiB
//   [393216, 409600)    : int   starts_h[B][2][NSEG]       16 KiB
//   [409600, 417792)    : int   counts_g[B][NSEG]           8 KiB
//   [417792, 679936)    : u16   permt[B][2][HALF]         256 KiB (bit-transposed, per half)
//   [679936, 2777088)   : float Sg[NROW][NSEG]              2 MiB
//   [2777088, 4874240)  : float Qg[NROW][NSEG]              2 MiB
//   [4874240, 4874752)  : double partials[64]

typedef unsigned short ushort8 __attribute__((ext_vector_type(8)));

__device__ __forceinline__ float sigmoidf(float x) {
    float e = __expf(-x);
    return __builtin_amdgcn_rcpf(1.0f + e);
}

// ---------- stage 1: per-chunk histograms + u8 ids + zero Sg/Qg ----------
__global__ __launch_bounds__(256) void hist_kernel(const float* __restrict__ mask,
                                                   int* __restrict__ hist,
                                                   unsigned char* __restrict__ ids8,
                                                   float* __restrict__ Sg,
                                                   float* __restrict__ Qg) {
    __shared__ int h[NSEG];
    const int blk = blockIdx.x;          // b*NCH + ch
    const int b = blk >> 5, ch = blk & 31;
    const int t = threadIdx.x;
    h[t] = 0;
    __syncthreads();

    const float2* m2 = (const float2*)(mask + (size_t)b * HW + ch * CHUNK);
    uchar2* o2 = (uchar2*)(ids8 + (size_t)b * HW + ch * CHUNK);
    float2 v = m2[t];
    int i0 = (int)v.x, i1 = (int)v.y;
    o2[t] = make_uchar2((unsigned char)i0, (unsigned char)i1);
    atomicAdd(&h[i0], 1);
    atomicAdd(&h[i1], 1);

    // zero this block's slice of Sg/Qg (2048 floats each)
    float4 z = {0.0f, 0.0f, 0.0f, 0.0f};
    float4* s4 = (float4*)(Sg + (size_t)blk * 2048);
    float4* q4 = (float4*)(Qg + (size_t)blk * 2048);
    #pragma unroll
    for (int j = 0; j < 2; ++j) { s4[j * 256 + t] = z; q4[j * 256 + t] = z; }

    __syncthreads();
    hist[blk * NSEG + t] = h[t];
}

// ---------- stage 2: per-half scan + position assignment ----------
// Positions within a (half, segment) may be assigned in any order (S,Q are sums).
__global__ __launch_bounds__(256) void assign_kernel(const unsigned char* __restrict__ ids8,
                                                     const int* __restrict__ hist,
                                                     int* __restrict__ starts_h,
                                                     int* __restrict__ counts_g,
                                                     unsigned short* __restrict__ permt) {
    __shared__ int sc[NSEG];
    __shared__ int off[NSEG];
    const int blk = blockIdx.x;
    const int b = blk >> 5, ch = blk & 31;
    const int half = ch >> 4;
    const int t = threadIdx.x;

    int tot = 0, tot_h = 0, pre = 0;
    for (int c2 = 0; c2 < NCH; ++c2) {
        int v = hist[((b << 5) + c2) * NSEG + t];
        tot += v;
        if ((c2 >> 4) == half) {
            tot_h += v;
            if (c2 < ch) pre += v;
        }
    }
    sc[t] = tot_h;
    __syncthreads();
    for (int o = 1; o < NSEG; o <<= 1) {          // Hillis-Steele inclusive scan
        int v = (t >= o) ? sc[t - o] : 0;
        __syncthreads();
        sc[t] += v;
        __syncthreads();
    }
    int st = sc[t] - tot_h;                       // segment start within half
    off[t] = st + pre;                            // this chunk's cursor
    if ((ch & 15) == 0) starts_h[(b * 2 + half) * NSEG + t] = st;
    if (ch == 0) counts_g[b * NSEG + t] = tot;
    __syncthreads();

    const unsigned char* idc = ids8 + (size_t)b * HW + ch * CHUNK;
    for (int j = 0; j < 2; ++j) {
        int pi = j * 256 + t;
        int id = idc[pi];
        int pos = atomicAdd(&off[id], 1);         // pos in [0, HALF)
        int p = (ch * CHUNK + pi) & (HALF - 1);   // local pixel index in half
        // bit-transpose pos [w:2|l:6|j8:2|r:3] -> sidx [w:2|j8:2|l:6|r:3]
        int sidx = ((pos >> 11) << 11) | (((pos >> 3) & 3) << 9) | (((pos >> 5) & 63) << 3) | (pos & 7);
        permt[(size_t)(b * 2 + half) * HALF + sidx] = (unsigned short)p;
    }
}

// ---------- main: stage half-row in LDS, sorted gather, global atomic flush ----------
__global__ __launch_bounds__(256, 4) void main_kernel(const float* __restrict__ x,
                                                      const unsigned short* __restrict__ permt,
                                                      const int* __restrict__ starts_h,
                                                      float* __restrict__ Sg,
                                                      float* __restrict__ Qg) {
    __shared__ float xs[HALF];          // 32 KiB: the (b,c) half-row, linear
    __shared__ int st[NSEG + 2];

    const int bid = blockIdx.x;
    const int rowpair = bid >> 1;       // b*C + c
    const int half = bid & 1;
    const int b = rowpair >> 8;
    const int t = threadIdx.x;
    const int w = t >> 6, l = t & 63;

    // async stage: 8 iters x 256 lanes x 16 B = 32 KiB, linear dest
    const float* xsrc = x + (size_t)rowpair * HW + half * HALF;
    for (int j = 0; j < 8; ++j) {
        int o = j * 1024 + t * 4;
        __builtin_amdgcn_global_load_lds(
            (const __attribute__((address_space(1))) void*)(xsrc + o),
            (__attribute__((address_space(3))) void*)(xs + o), 16, 0, 0);
    }

    // hoist perm loads (independent of xs) to overlap with stage drain
    const ushort8* pr = (const ushort8*)(permt + (size_t)(b * 2 + half) * HALF);
    ushort8 pp0 = pr[(w << 8) + (0 << 6) + l];
    ushort8 pp1 = pr[(w << 8) + (1 << 6) + l];
    ushort8 pp2 = pr[(w << 8) + (2 << 6) + l];
    ushort8 pp3 = pr[(w << 8) + (3 << 6) + l];

    st[t] = starts_h[(b * 2 + half) * NSEG + t];
    if (t == 0) st[NSEG] = HALF;
    __syncthreads();   // drains vmcnt -> xs ready

    // thread t owns sorted positions [32t, 32t+32) of this half
    int pos = t * 32;
    int lo = 0, hi = NSEG + 1;
    while (hi - lo > 1) {
        int mid = (lo + hi) >> 1;
        if (st[mid] <= pos) lo = mid; else hi = mid;
    }
    int s = lo;
    int nxt = st[s + 1];

    float* SgRow = Sg + (size_t)rowpair * NSEG;
    float* QgRow = Qg + (size_t)rowpair * NSEG;
    float S = 0.0f, Q = 0.0f;

    #define DO8(PP)                                              \
        _Pragma("unroll")                                        \
        for (int k = 0; k < 8; ++k) {                            \
            if (pos == nxt) {                                    \
                atomicAdd(&SgRow[s], S);                         \
                atomicAdd(&QgRow[s], Q);                         \
                S = 0.0f; Q = 0.0f;                              \
                do { ++s; } while (st[s + 1] <= pos);            \
                nxt = st[s + 1];                                 \
            }                                                    \
            float e = sigmoidf(xs[PP[k]]);                       \
            S += e; Q += e * e; ++pos;                           \
        }
    DO8(pp0) DO8(pp1) DO8(pp2) DO8(pp3)
    #undef DO8

    atomicAdd(&SgRow[s], S);
    atomicAdd(&QgRow[s], Q);
}

// ---------- final: loss = sum over bins of (Q - S^2/n), skip bg & empty ----------
__global__ __launch_bounds__(256) void final1_kernel(const float* __restrict__ Sg,
                                                     const float* __restrict__ Qg,
                                                     const int* __restrict__ counts_g,
                                                     double* __restrict__ partials) {
    __shared__ double wsum[4];
    const int blk = blockIdx.x, t = threadIdx.x;
    double acc = 0.0;
    for (int j = 0; j < 32; ++j) {
        int bin = blk * 8192 + j * 256 + t;       // 64 blocks x 8192 = 524288 bins
        int row = bin >> 8, s = bin & 255, b = row >> 8;
        int n = counts_g[b * NSEG + s];
        if (s < NSEG - 1 && n > 0) {
            double S = (double)Sg[bin], Q = (double)Qg[bin];
            acc += Q - S * S / (double)n;
        }
    }
    #pragma unroll
    for (int o = 32; o > 0; o >>= 1) acc += __shfl_down(acc, o);
    const int lane = t & 63, w = t >> 6;
    if (lane == 0) wsum[w] = acc;
    __syncthreads();
    if (t == 0) partials[blk] = wsum[0] + wsum[1] + wsum[2] + wsum[3];
}

__global__ __launch_bounds__(64) void final2_kernel(const double* __restrict__ partials,
                                                    float* __restrict__ out) {
    const int t = threadIdx.x;
    double p = partials[t];
    #pragma unroll
    for (int o = 32; o > 0; o >>= 1) p += __shfl_down(p, o);
    if (t == 0) out[0] = (float)(p / (double)((size_t)B * C * HW));
}

extern "C" void kernel_launch(void* const* d_in, const int* in_sizes, int n_in,
                              void* d_out, int out_size, void* d_ws, size_t ws_size,
                              hipStream_t stream) {
    const float* x = (const float*)d_in[0];
    const float* mask = (const float*)d_in[1];
    float* out = (float*)d_out;

    char* ws = (char*)d_ws;
    int* hist = (int*)ws;                                      // 256 KiB
    unsigned char* ids8 = (unsigned char*)(ws + 262144);       // 128 KiB
    int* starts_h = (int*)(ws + 393216);                       //  16 KiB
    int* counts_g = (int*)(ws + 409600);                       //   8 KiB
    unsigned short* permt = (unsigned short*)(ws + 417792);    // 256 KiB
    float* Sg = (float*)(ws + 679936);                         //   2 MiB
    float* Qg = (float*)(ws + 2777088);                        //   2 MiB
    double* partials = (double*)(ws + 4874240);                // 512 B

    hist_kernel<<<B * NCH, 256, 0, stream>>>(mask, hist, ids8, Sg, Qg);
    assign_kernel<<<B * NCH, 256, 0, stream>>>(ids8, hist, starts_h, counts_g, permt);
    main_kernel<<<NMAIN, 256, 0, stream>>>(x, permt, starts_h, Sg, Qg);
    final1_kernel<<<64, 256, 0, stream>>>(Sg, Qg, counts_g, partials);
    final2_kernel<<<1, 64, 0, stream>>>(partials, out);
}

// Round 10
// 209.193 us; speedup vs baseline: 1.3186x; 1.3186x over previous
//
#include <hip/hip_runtime.h>

#define B 8
#define C 256
#define HW 16384
#define HALF 8192
#define NSEG 256
#define NCH 32            // hist chunks per batch
#define CHUNK 512         // pixels per chunk
#define NROW (B * C)      // 2048 rows
#define NMAINBLK 512      // persistent main blocks (2 per CU)
#define ROWS_PER_BLK 4    // 512 * 4 = 2048 rows

// ws layout:
//   [0, 262144)         : int   hist[B][NCH][NSEG]        256 KiB
//   [262144, 393216)    : u8    ids8[B][HW]               128 KiB
//   [393216, 409600)    : int   starts_h[B][2][NSEG]       16 KiB
//   [409600, 417792)    : int   counts_g[B][NSEG]           8 KiB
//   [417792, 679936)    : u16   permt[B][2][HALF]         256 KiB (bit-transposed, per half)
//   [679936, 684032)    : double partials[512]              4 KiB

typedef unsigned short ushort8 __attribute__((ext_vector_type(8)));

__device__ __forceinline__ float sigmoidf(float x) {
    float e = __expf(-x);
    return __builtin_amdgcn_rcpf(1.0f + e);
}

// native LDS fp32 atomic add (avoids hipcc's CAS-loop expansion of atomicAdd)
__device__ __forceinline__ void ldsAddF32(float* a, float v) {
    __attribute__((address_space(3))) float* p3 =
        (__attribute__((address_space(3))) float*)a;
    asm volatile("ds_add_f32 %0, %1" :: "v"(p3), "v"(v));
}

// phase barriers: keep vmcnt in flight where safe (no __syncthreads mid-loop)
#define BAR_VMLG() asm volatile("s_waitcnt vmcnt(0) lgkmcnt(0)\ns_barrier" ::: "memory")
#define BAR_LG()   asm volatile("s_waitcnt lgkmcnt(0)\ns_barrier" ::: "memory")

// ---------- stage 1: per-chunk histograms + u8 ids ----------
__global__ __launch_bounds__(256) void hist_kernel(const float* __restrict__ mask,
                                                   int* __restrict__ hist,
                                                   unsigned char* __restrict__ ids8) {
    __shared__ int h[NSEG];
    const int blk = blockIdx.x;          // b*NCH + ch
    const int b = blk >> 5, ch = blk & 31;
    const int t = threadIdx.x;
    h[t] = 0;
    __syncthreads();

    const float2* m2 = (const float2*)(mask + (size_t)b * HW + ch * CHUNK);
    uchar2* o2 = (uchar2*)(ids8 + (size_t)b * HW + ch * CHUNK);
    float2 v = m2[t];
    int i0 = (int)v.x, i1 = (int)v.y;
    o2[t] = make_uchar2((unsigned char)i0, (unsigned char)i1);
    atomicAdd(&h[i0], 1);
    atomicAdd(&h[i1], 1);
    __syncthreads();
    hist[blk * NSEG + t] = h[t];
}

// ---------- stage 2: per-half scan + position assignment ----------
__global__ __launch_bounds__(256) void assign_kernel(const unsigned char* __restrict__ ids8,
                                                     const int* __restrict__ hist,
                                                     int* __restrict__ starts_h,
                                                     int* __restrict__ counts_g,
                                                     unsigned short* __restrict__ permt) {
    __shared__ int sc[NSEG];
    __shared__ int off[NSEG];
    const int blk = blockIdx.x;
    const int b = blk >> 5, ch = blk & 31;
    const int half = ch >> 4;
    const int t = threadIdx.x;

    int tot = 0, tot_h = 0, pre = 0;
    for (int c2 = 0; c2 < NCH; ++c2) {
        int v = hist[((b << 5) + c2) * NSEG + t];
        tot += v;
        if ((c2 >> 4) == half) {
            tot_h += v;
            if (c2 < ch) pre += v;
        }
    }
    sc[t] = tot_h;
    __syncthreads();
    for (int o = 1; o < NSEG; o <<= 1) {          // Hillis-Steele inclusive scan
        int v = (t >= o) ? sc[t - o] : 0;
        __syncthreads();
        sc[t] += v;
        __syncthreads();
    }
    int st = sc[t] - tot_h;                       // segment start within half
    off[t] = st + pre;                            // this chunk's cursor
    if ((ch & 15) == 0) starts_h[(b * 2 + half) * NSEG + t] = st;
    if (ch == 0) counts_g[b * NSEG + t] = tot;
    __syncthreads();

    const unsigned char* idc = ids8 + (size_t)b * HW + ch * CHUNK;
    for (int j = 0; j < 2; ++j) {
        int pi = j * 256 + t;
        int id = idc[pi];
        int pos = atomicAdd(&off[id], 1);         // pos in [0, HALF)
        int p = (ch * CHUNK + pi) & (HALF - 1);   // local pixel index in half
        // bit-transpose pos [w:2|l:6|g:2|r:3] -> sidx [w:2|g:2|l:6|r:3]
        int sidx = ((pos >> 11) << 11) | (((pos >> 3) & 3) << 9) | (((pos >> 5) & 63) << 3) | (pos & 7);
        permt[(size_t)(b * 2 + half) * HALF + sidx] = (unsigned short)p;
    }
}

// ---------- main: persistent, double-buffered stage/gather pipeline ----------

#define STEP(ST, XV) {                                               \
    if (pos == nxt) {                                                \
        ldsAddF32(&bS[s], S); ldsAddF32(&bQ[s], Q);                  \
        S = 0.0f; Q = 0.0f;                                          \
        do { ++s; } while (ST[s + 1] <= pos);                        \
        nxt = ST[s + 1];                                             \
    }                                                                \
    float e = sigmoidf(XV);                                          \
    S += e; Q += e * e; ++pos;                                       \
}

#define GRP(BUF, ST, PP) {                                           \
    float xv0 = BUF[PP[0]], xv1 = BUF[PP[1]], xv2 = BUF[PP[2]],      \
          xv3 = BUF[PP[3]], xv4 = BUF[PP[4]], xv5 = BUF[PP[5]],      \
          xv6 = BUF[PP[6]], xv7 = BUF[PP[7]];                        \
    STEP(ST, xv0) STEP(ST, xv1) STEP(ST, xv2) STEP(ST, xv3)          \
    STEP(ST, xv4) STEP(ST, xv5) STEP(ST, xv6) STEP(ST, xv7)          \
}

#define GATHER(BUF, ST, P0, P1, P2, P3) {                            \
    int pos = t * 32;                                                \
    int lo = 0, hi = NSEG;                                           \
    while (hi - lo > 1) {                                            \
        int mid = (lo + hi) >> 1;                                    \
        if (ST[mid] <= pos) lo = mid; else hi = mid;                 \
    }                                                                \
    int s = lo;                                                      \
    int nxt = ST[s + 1];                                             \
    float S = 0.0f, Q = 0.0f;                                        \
    GRP(BUF, ST, P0) GRP(BUF, ST, P1) GRP(BUF, ST, P2) GRP(BUF, ST, P3) \
    ldsAddF32(&bS[s], S); ldsAddF32(&bQ[s], Q);                      \
}

#define STAGE8(SRC, DST) {                                           \
    _Pragma("unroll")                                                \
    for (int j = 0; j < 8; ++j) {                                    \
        int o = j * 1024 + t * 4;                                    \
        __builtin_amdgcn_global_load_lds(                            \
            (const __attribute__((address_space(1))) void*)((SRC) + o), \
            (__attribute__((address_space(3))) void*)((DST) + o), 16, 0, 0); \
    }                                                                \
}

__global__ __launch_bounds__(256) void main_kernel(const float* __restrict__ x,
                                                   const unsigned short* __restrict__ permt,
                                                   const int* __restrict__ starts_h,
                                                   const int* __restrict__ counts_g,
                                                   double* __restrict__ partials) {
    __shared__ float buf0[HALF];        // 32 KiB
    __shared__ float buf1[HALF];        // 32 KiB
    __shared__ int st0[NSEG + 1];
    __shared__ int st1[NSEG + 1];
    __shared__ float bS[NSEG];
    __shared__ float bQ[NSEG];
    __shared__ double wsum[4];

    const int blk = blockIdx.x;
    const int rbase = blk * ROWS_PER_BLK;
    const int b = rbase >> 8;
    const int t = threadIdx.x;
    const int w = t >> 6, l = t & 63;

    // ---- prologue: stage row0/half0; load per-batch tables once ----
    STAGE8(x + (size_t)rbase * HW, buf0);

    const ushort8* prA = (const ushort8*)(permt + (size_t)(b * 2 + 0) * HALF);
    const ushort8* prB = (const ushort8*)(permt + (size_t)(b * 2 + 1) * HALF);
    ushort8 pa0 = prA[(w << 8) + (0 << 6) + l];
    ushort8 pa1 = prA[(w << 8) + (1 << 6) + l];
    ushort8 pa2 = prA[(w << 8) + (2 << 6) + l];
    ushort8 pa3 = prA[(w << 8) + (3 << 6) + l];
    ushort8 pb0 = prB[(w << 8) + (0 << 6) + l];
    ushort8 pb1 = prB[(w << 8) + (1 << 6) + l];
    ushort8 pb2 = prB[(w << 8) + (2 << 6) + l];
    ushort8 pb3 = prB[(w << 8) + (3 << 6) + l];

    st0[t] = starts_h[(b * 2 + 0) * NSEG + t];
    st1[t] = starts_h[(b * 2 + 1) * NSEG + t];
    if (t == 0) { st0[NSEG] = HALF; st1[NSEG] = HALF; }
    bS[t] = 0.0f;
    bQ[t] = 0.0f;

    int n_t = counts_g[b * NSEG + t];
    double rn = (n_t > 0) ? 1.0 / (double)n_t : 0.0;
    double acc = 0.0;

    for (int r = 0; r < ROWS_PER_BLK; ++r) {
        const float* rowp = x + (size_t)(rbase + r) * HW;

        // ---- even half: buf0 ready after barrier; stage odd half into buf1 ----
        BAR_VMLG();
        STAGE8(rowp + HALF, buf1);
        GATHER(buf0, st0, pa0, pa1, pa2, pa3);

        // ---- odd half: buf1 ready; stage next row's even half into buf0 ----
        BAR_VMLG();
        if (r + 1 < ROWS_PER_BLK) {
            STAGE8(rowp + HW, buf0);   // next row, half 0
        }
        GATHER(buf1, st1, pb0, pb1, pb2, pb3);

        // ---- row epilogue: combine bins, accumulate, rezero ----
        BAR_LG();                       // drains ds_adds; does NOT drain the stage
        {
            float Sv = bS[t], Qv = bQ[t];
            if (t < NSEG - 1) acc += (double)Qv - (double)Sv * (double)Sv * rn;
            bS[t] = 0.0f;
            bQ[t] = 0.0f;
        }
    }

    // ---- block reduce 256 per-thread doubles ----
    double p = acc;
    #pragma unroll
    for (int o = 32; o > 0; o >>= 1) p += __shfl_down(p, o);
    if (l == 0) wsum[w] = p;
    __syncthreads();
    if (t == 0) partials[blk] = wsum[0] + wsum[1] + wsum[2] + wsum[3];
}

// ---------- final: reduce 512 block partials ----------
__global__ __launch_bounds__(256) void final_kernel(const double* __restrict__ partials,
                                                    float* __restrict__ out) {
    __shared__ double wsum[4];
    const int t = threadIdx.x;
    double p = partials[t] + partials[t + 256];
    #pragma unroll
    for (int o = 32; o > 0; o >>= 1) p += __shfl_down(p, o);
    const int lane = t & 63, w = t >> 6;
    if (lane == 0) wsum[w] = p;
    __syncthreads();
    if (t == 0) {
        double total = wsum[0] + wsum[1] + wsum[2] + wsum[3];
        out[0] = (float)(total / (double)((size_t)B * C * HW));
    }
}

extern "C" void kernel_launch(void* const* d_in, const int* in_sizes, int n_in,
                              void* d_out, int out_size, void* d_ws, size_t ws_size,
                              hipStream_t stream) {
    const float* x = (const float*)d_in[0];
    const float* mask = (const float*)d_in[1];
    float* out = (float*)d_out;

    char* ws = (char*)d_ws;
    int* hist = (int*)ws;                                      // 256 KiB
    unsigned char* ids8 = (unsigned char*)(ws + 262144);       // 128 KiB
    int* starts_h = (int*)(ws + 393216);                       //  16 KiB
    int* counts_g = (int*)(ws + 409600);                       //   8 KiB
    unsigned short* permt = (unsigned short*)(ws + 417792);    // 256 KiB
    double* partials = (double*)(ws + 679936);                 //   4 KiB

    hist_kernel<<<B * NCH, 256, 0, stream>>>(mask, hist, ids8);
    assign_kernel<<<B * NCH, 256, 0, stream>>>(ids8, hist, starts_h, counts_g, permt);
    main_kernel<<<NMAINBLK, 256, 0, stream>>>(x, permt, starts_h, counts_g, partials);
    final_kernel<<<1, 256, 0, stream>>>(partials, out);
}

// Round 11
// 208.578 us; speedup vs baseline: 1.3225x; 1.0029x over previous
//
#include <hip/hip_runtime.h>

#define B 8
#define C 256
#define HW 16384
#define HALF 8192
#define PADN 16384        // padded sorted slots per half: 8192 + 256*31 = 16128 <= 16384 always
#define NSEG 256
#define NCH 32            // hist chunks per batch
#define CHUNK 512         // pixels per chunk
#define NROW (B * C)      // 2048 rows
#define NMAINBLK 512      // 2 per CU
#define ROWS_PER_BLK 4    // 512 * 4 = 2048 rows

// ws layout:
//   [0, 262144)        : int   hist[B][NCH][NSEG]       256 KiB
//   [262144, 393216)   : u8    ids8[B][HW]              128 KiB
//   [393216, 401408)   : int   counts_g[B][NSEG]          8 KiB
//   [401408, 409600)   : u8    segtab[B][2][512]          8 KiB (group -> segment, 0xFF unused)
//   [409600, 933888)   : u16   permp[B][2][PADN]        512 KiB (padded, bit-transposed, 0xFFFF pad)
//   [933888, 937984)   : double partials[512]             4 KiB

typedef unsigned short ushort8 __attribute__((ext_vector_type(8)));

__device__ __forceinline__ float sigmoidf(float x) {
    float e = __expf(-x);
    return __builtin_amdgcn_rcpf(1.0f + e);
}

// native LDS fp32 atomic add
__device__ __forceinline__ void ldsAddF32(float* a, float v) {
    __attribute__((address_space(3))) float* p3 =
        (__attribute__((address_space(3))) float*)a;
    asm volatile("ds_add_f32 %0, %1" :: "v"(p3), "v"(v));
}

#define BAR_VMLG() asm volatile("s_waitcnt vmcnt(0) lgkmcnt(0)\ns_barrier" ::: "memory")
#define BAR_LG()   asm volatile("s_waitcnt lgkmcnt(0)\ns_barrier" ::: "memory")

// ---------- stage 1: per-chunk histograms + u8 ids + sentinel prefills ----------
__global__ __launch_bounds__(256) void hist_kernel(const float* __restrict__ mask,
                                                   int* __restrict__ hist,
                                                   unsigned char* __restrict__ ids8,
                                                   unsigned int* __restrict__ permp32,
                                                   unsigned int* __restrict__ segtab32) {
    __shared__ int h[NSEG];
    const int blk = blockIdx.x;          // b*NCH + ch
    const int b = blk >> 5, ch = blk & 31;
    const int t = threadIdx.x;
    h[t] = 0;
    __syncthreads();

    const float2* m2 = (const float2*)(mask + (size_t)b * HW + ch * CHUNK);
    uchar2* o2 = (uchar2*)(ids8 + (size_t)b * HW + ch * CHUNK);
    float2 v = m2[t];
    int i0 = (int)v.x, i1 = (int)v.y;
    o2[t] = make_uchar2((unsigned char)i0, (unsigned char)i1);
    atomicAdd(&h[i0], 1);
    atomicAdd(&h[i1], 1);

    // prefill permp with 0xFFFF sentinels: 131072 u32 total / 256 blocks = 512 u32 each
    unsigned int* pp = permp32 + (size_t)blk * 512;
    pp[t] = 0xFFFFFFFFu;
    pp[t + 256] = 0xFFFFFFFFu;
    // prefill segtab with 0xFF: 2048 u32 total / 256 blocks = 8 each
    if (t < 8) segtab32[blk * 8 + t] = 0xFFFFFFFFu;

    __syncthreads();
    hist[blk * NSEG + t] = h[t];
}

// ---------- stage 2: padded scan + position assignment + group->seg table ----------
// Positions within a (half, segment) may be assigned in any order (S,Q are sums).
__global__ __launch_bounds__(256) void assign_kernel(const unsigned char* __restrict__ ids8,
                                                     const int* __restrict__ hist,
                                                     int* __restrict__ counts_g,
                                                     unsigned char* __restrict__ segtab,
                                                     unsigned short* __restrict__ permp) {
    __shared__ int sc[NSEG];
    __shared__ int off[NSEG];
    const int blk = blockIdx.x;
    const int b = blk >> 5, ch = blk & 31;
    const int half = ch >> 4;
    const int t = threadIdx.x;

    int tot = 0, tot_h = 0, pre = 0;
    for (int c2 = 0; c2 < NCH; ++c2) {
        int v = hist[((b << 5) + c2) * NSEG + t];
        tot += v;
        if ((c2 >> 4) == half) {
            tot_h += v;
            if (c2 < ch) pre += v;
        }
    }
    int pad32 = (tot_h + 31) & ~31;               // segment padded to multiple of 32
    sc[t] = pad32;
    __syncthreads();
    for (int o = 1; o < NSEG; o <<= 1) {          // Hillis-Steele inclusive scan
        int v = (t >= o) ? sc[t - o] : 0;
        __syncthreads();
        sc[t] += v;
        __syncthreads();
    }
    int pstart = sc[t] - pad32;                   // padded segment start (multiple of 32)
    off[t] = pstart + pre;                        // this chunk's write cursor
    if (ch == 0) counts_g[b * NSEG + t] = tot;
    if ((ch & 15) == 0) {                         // one block per (b,half)
        for (int g = pstart >> 5; g < (pstart + pad32) >> 5; ++g)
            segtab[(b * 2 + half) * 512 + g] = (unsigned char)t;
    }
    __syncthreads();

    const unsigned char* idc = ids8 + (size_t)b * HW + ch * CHUNK;
    unsigned short* pp = permp + (size_t)(b * 2 + half) * PADN;
    for (int j = 0; j < 2; ++j) {
        int pi = j * 256 + t;
        int id = idc[pi];
        int pos = atomicAdd(&off[id], 1);         // padded slot in [0, PADN)
        int p = (ch * CHUNK + pi) & (HALF - 1);   // local pixel index in half
        // bit-transpose slot [w:3|l:6|j:2|k:3] -> store [w:3|j:2|l:6|k:3]
        // so main's per-wave ushort8 reads are fully coalesced.
        int sidx = ((pos >> 11) << 11) | (((pos >> 3) & 3) << 9) | (((pos >> 5) & 63) << 3) | (pos & 7);
        pp[sidx] = (unsigned short)p;
    }
}

// ---------- main: persistent dbuf pipeline, branchless padded gather ----------

#define PAD8(BUF, PP) {                                              \
    _Pragma("unroll")                                                \
    for (int k = 0; k < 8; ++k) {                                    \
        int p = PP[k];                                               \
        float e = sigmoidf(BUF[p & (HALF - 1)]);                     \
        e = (p == 0xFFFF) ? 0.0f : e;                                \
        S += e; Q += e * e;                                          \
    }                                                                \
}

#define GATHERP(BUF, SG, P0, P1, P2, P3) {                           \
    float S = 0.0f, Q = 0.0f;                                        \
    PAD8(BUF, P0) PAD8(BUF, P1) PAD8(BUF, P2) PAD8(BUF, P3)          \
    ldsAddF32(&bS[SG], S); ldsAddF32(&bQ[SG], Q);                    \
}

#define STAGE4(SRC, DST) {                                           \
    _Pragma("unroll")                                                \
    for (int j = 0; j < 4; ++j) {                                    \
        int o = j * 2048 + t * 4;                                    \
        __builtin_amdgcn_global_load_lds(                            \
            (const __attribute__((address_space(1))) void*)((SRC) + o), \
            (__attribute__((address_space(3))) void*)((DST) + o), 16, 0, 0); \
    }                                                                \
}

__global__ __launch_bounds__(512) void main_kernel(const float* __restrict__ x,
                                                   const unsigned short* __restrict__ permp,
                                                   const unsigned char* __restrict__ segtab,
                                                   const int* __restrict__ counts_g,
                                                   double* __restrict__ partials) {
    __shared__ float buf0[HALF];        // 32 KiB
    __shared__ float buf1[HALF];        // 32 KiB
    __shared__ float bS[NSEG];
    __shared__ float bQ[NSEG];
    __shared__ double wsum[8];

    const int blk = blockIdx.x;
    const int rbase = blk * ROWS_PER_BLK;
    const int b = rbase >> 8;
    const int t = threadIdx.x;
    const int w = t >> 6, l = t & 63;

    // ---- prologue: stage row0/half0; load per-batch tables once ----
    STAGE4(x + (size_t)rbase * HW, buf0);

    const ushort8* prA = (const ushort8*)(permp + (size_t)(b * 2 + 0) * PADN);
    const ushort8* prB = (const ushort8*)(permp + (size_t)(b * 2 + 1) * PADN);
    ushort8 pa0 = prA[(w << 8) + (0 << 6) + l];
    ushort8 pa1 = prA[(w << 8) + (1 << 6) + l];
    ushort8 pa2 = prA[(w << 8) + (2 << 6) + l];
    ushort8 pa3 = prA[(w << 8) + (3 << 6) + l];
    ushort8 pb0 = prB[(w << 8) + (0 << 6) + l];
    ushort8 pb1 = prB[(w << 8) + (1 << 6) + l];
    ushort8 pb2 = prB[(w << 8) + (2 << 6) + l];
    ushort8 pb3 = prB[(w << 8) + (3 << 6) + l];

    const int sgA = segtab[(b * 2 + 0) * 512 + t];   // 0xFF -> 255 = ignored bg bin
    const int sgB = segtab[(b * 2 + 1) * 512 + t];

    if (t < NSEG) { bS[t] = 0.0f; bQ[t] = 0.0f; }
    int n_t = (t < NSEG) ? counts_g[b * NSEG + t] : 0;
    double rn = (n_t > 0) ? 1.0 / (double)n_t : 0.0;
    double acc = 0.0;

    for (int r = 0; r < ROWS_PER_BLK; ++r) {
        const float* rowp = x + (size_t)(rbase + r) * HW;

        // ---- even half: buf0 ready after barrier; stage odd half into buf1 ----
        BAR_VMLG();
        STAGE4(rowp + HALF, buf1);
        GATHERP(buf0, sgA, pa0, pa1, pa2, pa3);

        // ---- odd half: buf1 ready; stage next row's even half into buf0 ----
        BAR_VMLG();
        if (r + 1 < ROWS_PER_BLK) {
            STAGE4(rowp + HW, buf0);   // next row, half 0
        }
        GATHERP(buf1, sgB, pb0, pb1, pb2, pb3);

        // ---- row epilogue: combine bins, accumulate, rezero ----
        BAR_LG();                       // drains ds_adds; does NOT drain the stage
        if (t < NSEG) {
            float Sv = bS[t], Qv = bQ[t];
            if (t < NSEG - 1) acc += (double)Qv - (double)Sv * (double)Sv * rn;
            bS[t] = 0.0f;
            bQ[t] = 0.0f;
        }
    }

    // ---- block reduce (8 waves) ----
    double p = acc;
    #pragma unroll
    for (int o = 32; o > 0; o >>= 1) p += __shfl_down(p, o);
    if (l == 0) wsum[w] = p;
    __syncthreads();
    if (t == 0) {
        double tt = 0.0;
        #pragma unroll
        for (int i = 0; i < 8; ++i) tt += wsum[i];
        partials[blk] = tt;
    }
}

// ---------- final: reduce 512 block partials ----------
__global__ __launch_bounds__(256) void final_kernel(const double* __restrict__ partials,
                                                    float* __restrict__ out) {
    __shared__ double wsum[4];
    const int t = threadIdx.x;
    double p = partials[t] + partials[t + 256];
    #pragma unroll
    for (int o = 32; o > 0; o >>= 1) p += __shfl_down(p, o);
    const int lane = t & 63, w = t >> 6;
    if (lane == 0) wsum[w] = p;
    __syncthreads();
    if (t == 0) {
        double total = wsum[0] + wsum[1] + wsum[2] + wsum[3];
        out[0] = (float)(total / (double)((size_t)B * C * HW));
    }
}

extern "C" void kernel_launch(void* const* d_in, const int* in_sizes, int n_in,
                              void* d_out, int out_size, void* d_ws, size_t ws_size,
                              hipStream_t stream) {
    const float* x = (const float*)d_in[0];
    const float* mask = (const float*)d_in[1];
    float* out = (float*)d_out;

    char* ws = (char*)d_ws;
    int* hist = (int*)ws;                                      // 256 KiB
    unsigned char* ids8 = (unsigned char*)(ws + 262144);       // 128 KiB
    int* counts_g = (int*)(ws + 393216);                       //   8 KiB
    unsigned char* segtab = (unsigned char*)(ws + 401408);     //   8 KiB
    unsigned short* permp = (unsigned short*)(ws + 409600);    // 512 KiB
    double* partials = (double*)(ws + 933888);                 //   4 KiB

    hist_kernel<<<B * NCH, 256, 0, stream>>>(mask, hist, ids8,
                                             (unsigned int*)permp, (unsigned int*)segtab);
    assign_kernel<<<B * NCH, 256, 0, stream>>>(ids8, hist, counts_g, segtab, permp);
    main_kernel<<<NMAINBLK, 512, 0, stream>>>(x, permp, segtab, counts_g, partials);
    final_kernel<<<1, 256, 0, stream>>>(partials, out);
}